// Round 12
// baseline (171.237 us; speedup 1.0000x reference)
//
#include <hip/hip_runtime.h>
#include <hip/hip_bf16.h>
#include <math.h>

#define NB 16
#define NC 64
#define NH 160
#define NW 160

typedef __attribute__((ext_vector_type(8))) short bf16x8;
typedef __attribute__((ext_vector_type(4))) float f32x4;
typedef __attribute__((ext_vector_type(8))) unsigned short u16x8;
typedef __attribute__((ext_vector_type(4))) unsigned short u16x4;

__device__ __forceinline__ unsigned short f2bf(float v) {
  union { __hip_bfloat16 b; unsigned short u; } cv; cv.b = __float2bfloat16(v); return cv.u;
}
__device__ __forceinline__ float bf2f(unsigned short u) {
  union { unsigned u; float f; } cv; cv.u = ((unsigned)u) << 16; return cv.f;
}

// lgkm-only barrier: no vmcnt drain of global stores (T3/T4); rule-18 fencing
#define LGKM_BARRIER()                                  \
  asm volatile("s_waitcnt lgkmcnt(0)" ::: "memory");    \
  __builtin_amdgcn_sched_barrier(0);                    \
  __builtin_amdgcn_s_barrier();                         \
  __builtin_amdgcn_sched_barrier(0);

// ---------------------------------------------------------------------------
// Pack kernel: apkA/apkB (A-fragment weights), wqt (wq transposed), wkst.
// ---------------------------------------------------------------------------
__global__ void pack_w_kernel3(const float* __restrict__ wA, const float* __restrict__ wB,
                               const float* __restrict__ wq, const float* __restrict__ wk,
                               unsigned short* __restrict__ apkA, unsigned short* __restrict__ apkB,
                               float* __restrict__ wqt, float* __restrict__ wkst) {
  int idx = blockIdx.x * 256 + threadIdx.x;
  if (idx < 2 * 36864) {
    const float* w = (idx < 36864) ? wA : wB;
    unsigned short* apk = (idx < 36864) ? apkA : apkB;
    int i = (idx < 36864) ? idx : idx - 36864;
    int j = i & 7, l = (i >> 3) & 63, rest = i >> 9;
    int ks = rest % 18, ct = rest / 18;
    int cih = ks & 1, tap = ks >> 1, kh = tap / 3, kw = tap % 3;
    int co = ct * 16 + (l & 15), ci = cih * 32 + (l >> 4) * 8 + j;
    apk[i] = f2bf(w[(((size_t)co * NC + ci) * 3 + kh) * 3 + kw]);
  } else if (idx < 3 * 36864) {
    int i2 = idx - 2 * 36864;
    int c = i2 & 63, tau = i2 >> 6;
    int i = tau & 63, jj = tau >> 6;
    wqt[i2] = wq[(size_t)c * 576 + i * 9 + jj];
  } else if (idx < 3 * 36864 + 576) {
    int i3 = idx - 3 * 36864;
    int i = i3 & 63, jj = i3 >> 6;
    float s = 0.f;
    for (int cj = 0; cj < NC; ++cj) s += wk[(size_t)cj * 576 + i * 9 + jj];
    wkst[i3] = s;
  }
}

// ---------------------------------------------------------------------------
// Sliding-row implicit-GEMM conv3x3 (SAME) via MFMA 16x16x32 bf16.
// R9 structure VERBATIM (best measured): issue-at-window-start,
// commit-at-window-end, lgkm-only barriers, epi dbuf, fused NCHW staging
// in conv1, all 18 weight frags resident.
// ---------------------------------------------------------------------------
template<bool FINAL>
__global__ __launch_bounds__(256, 2) void conv3x3_mfma7(
    const unsigned short* __restrict__ in_nhwc, const float* __restrict__ in_nchw,
    const unsigned short* __restrict__ apk,
    const float* __restrict__ gg, const float* __restrict__ bbeta,
    const float* __restrict__ mmean, const float* __restrict__ vvar,
    void* __restrict__ outv, const float* __restrict__ scores,
    const float* __restrict__ xres, float* __restrict__ colpart)
{
  __shared__ unsigned short ring[6 * 34 * 64];                 // 26,112 B
  __shared__ unsigned short epi[FINAL ? 8 : 2 * 64 * 72];      // 18,432 B (conv1, dbuf)
  __shared__ f32x4 csv[FINAL ? 1 : 512];                       // 8,192 B (conv1)

  const int t = threadIdx.x, lane = t & 63, wave = t >> 6;
  const int q = lane >> 4, col = lane & 15;

  int g = blockIdx.x;                    // 1280 = 8 * 160, bijective XCD swizzle
  int sw = (g & 7) * 160 + (g >> 3);
  const int b = sw / 80;
  int rem = sw % 80;
  const int h0 = (rem / 5) * 10, w0 = (rem % 5) * 32;

  float scR[4], shR[4], scoR[4];
#pragma unroll
  for (int r = 0; r < 4; ++r) {
    int co = wave * 16 + q * 4 + r;
    float s = gg[co] * rsqrtf(vvar[co] + 1e-5f);
    scR[r] = s; shR[r] = bbeta[co] - mmean[co] * s;
    scoR[r] = FINAL ? scores[b * NC + co] : 0.f;
  }

  bf16x8 wf[18];
#pragma unroll
  for (int ks = 0; ks < 18; ++ks)
    wf[ks] = *(const bf16x8*)&apk[((size_t)(wave * 18 + ks) * 64 + lane) * 8];

  const unsigned short* inb = FINAL ? in_nhwc + (size_t)b * NH * NW * 64 : nullptr;
  const float* xb = FINAL ? nullptr : in_nchw + (size_t)b * NC * NH * NW;

#define SLOT(R) ((int)((unsigned)((R) + 1) % 6u) * 2176)

  // ---- FINAL staging: NHWC bf16, u16x8 vector loads ----
#define STGF_ISSUE(ROW, V0, V1, A0, A1)                                       \
  { int row_ = (ROW);                                                         \
    bool rowok_ = (unsigned)row_ < (unsigned)NH;                              \
    int slot_ = SLOT(row_);                                                   \
    { int wcc = t >> 3, s8 = t & 7; int wsrc = w0 + wcc - 1;                  \
      A0 = slot_ + wcc * 64 + ((s8 ^ (wcc & 7)) << 3);                        \
      V0 = (u16x8){};                                                         \
      if (rowok_ && (unsigned)wsrc < (unsigned)NW)                            \
        V0 = *(const u16x8*)&inb[((size_t)row_ * NW + wsrc) * 64 + s8 * 8];   \
    }                                                                         \
    if (t < 16) { int c = 256 + t; int wcc = c >> 3, s8 = c & 7;              \
      int wsrc = w0 + wcc - 1;                                                \
      A1 = slot_ + wcc * 64 + ((s8 ^ (wcc & 7)) << 3);                        \
      V1 = (u16x8){};                                                         \
      if (rowok_ && (unsigned)wsrc < (unsigned)NW)                            \
        V1 = *(const u16x8*)&inb[((size_t)row_ * NW + wsrc) * 64 + s8 * 8];   \
    } }
#define STGF_COMMIT(V0, V1, A0, A1)                                           \
  *(u16x8*)&ring[A0] = V0;                                                    \
  if (t < 16) *(u16x8*)&ring[A1] = V1;

  // ---- conv1 staging: NCHW f32 x, 8 dword loads (34-lane coalesced runs) ----
#define STG1_ISSUE(ROW, F0, F1, A0, A1)                                       \
  { int row_ = (ROW);                                                         \
    bool rowok_ = (unsigned)row_ < (unsigned)NH;                              \
    int slot_ = SLOT(row_);                                                   \
    { int wcc = t % 34, s8 = t / 34; int wsrc = w0 + wcc - 1;                 \
      A0 = slot_ + wcc * 64 + ((s8 ^ (wcc & 7)) << 3);                        \
      bool ok_ = rowok_ && (unsigned)wsrc < (unsigned)NW;                     \
      if (ok_) {                                                              \
        const float* xp_ = xb + ((size_t)(s8 * 8) * NH + row_) * NW + wsrc;   \
        _Pragma("unroll") for (int j_ = 0; j_ < 8; ++j_)                      \
          F0[j_] = xp_[(size_t)j_ * NH * NW];                                 \
      } else {                                                                \
        _Pragma("unroll") for (int j_ = 0; j_ < 8; ++j_) F0[j_] = 0.f;        \
      }                                                                       \
    }                                                                         \
    if (t < 16) { int wcc = 18 + t; int wsrc = w0 + wcc - 1;                  \
      A1 = slot_ + wcc * 64 + ((7 ^ (wcc & 7)) << 3);                         \
      bool ok_ = rowok_ && (unsigned)wsrc < (unsigned)NW;                     \
      if (ok_) {                                                              \
        const float* xp_ = xb + ((size_t)56 * NH + row_) * NW + wsrc;         \
        _Pragma("unroll") for (int j_ = 0; j_ < 8; ++j_)                      \
          F1[j_] = xp_[(size_t)j_ * NH * NW];                                 \
      } else {                                                                \
        _Pragma("unroll") for (int j_ = 0; j_ < 8; ++j_) F1[j_] = 0.f;        \
      }                                                                       \
    } }
#define STG1_COMMIT(F0, F1, A0, A1)                                           \
  { u16x8 pv_;                                                                \
    _Pragma("unroll") for (int j_ = 0; j_ < 8; ++j_) pv_[j_] = f2bf(F0[j_]);  \
    *(u16x8*)&ring[A0] = pv_; }                                               \
  if (t < 16) { u16x8 pv_;                                                    \
    _Pragma("unroll") for (int j_ = 0; j_ < 8; ++j_) pv_[j_] = f2bf(F1[j_]);  \
    *(u16x8*)&ring[A1] = pv_; }

  if constexpr (!FINAL) {
    csv[t] = (f32x4){0.f, 0.f, 0.f, 0.f};
    csv[t + 256] = (f32x4){0.f, 0.f, 0.f, 0.f};
  }

  // prologue: stage rows h0-1 .. h0+2
  if constexpr (FINAL) {
    for (int rr = -1; rr <= 2; ++rr) {
      u16x8 v0, v1 = {}; int a0, a1 = 0;
      STGF_ISSUE(h0 + rr, v0, v1, a0, a1)
      STGF_COMMIT(v0, v1, a0, a1)
    }
  } else {
    for (int rr = -1; rr <= 2; ++rr) {
      float f0[8], f1[8]; int a0, a1 = 0;
      STG1_ISSUE(h0 + rr, f0, f1, a0, a1)
      STG1_COMMIT(f0, f1, a0, a1)
    }
  }
  LGKM_BARRIER()

  for (int wi = 0; wi < 5; ++wi) {
    const int h = h0 + wi * 2;
    const bool doS = (wi < 4);

    u16x8 va0, va1 = {}, vb0, vb1 = {}; int aa0, aa1 = 0, ab0, ab1 = 0;
    float fa0[8], fa1[8], fb0[8], fb1[8];
    if (doS) {
      if constexpr (FINAL) {
        STGF_ISSUE(h + 3, va0, va1, aa0, aa1)
        STGF_ISSUE(h + 4, vb0, vb1, ab0, ab1)
      } else {
        STG1_ISSUE(h + 3, fa0, fa1, aa0, aa1)
        STG1_ISSUE(h + 4, fb0, fb1, ab0, ab1)
      }
    }

    const int sl[4] = { SLOT(h - 1), SLOT(h), SLOT(h + 1), SLOT(h + 2) };
    f32x4 acc[2][2];
#pragma unroll
    for (int o = 0; o < 2; ++o) { acc[o][0] = (f32x4){0,0,0,0}; acc[o][1] = (f32x4){0,0,0,0}; }

#pragma unroll
    for (int ri = 0; ri < 4; ++ri) {
#pragma unroll
      for (int kw = 0; kw < 3; ++kw) {
#pragma unroll
        for (int cih = 0; cih < 2; ++cih) {
          const int wcb = col + kw;
          const int ea = sl[ri] + wcb * 64 + (((cih << 2) + q) ^ (wcb & 7)) * 8;
          const bf16x8* bp = (const bf16x8*)&ring[ea];
          bf16x8 B0 = bp[0], B1 = bp[128];
          if (ri <= 2) {
            const int ks = (ri * 3 + kw) * 2 + cih;
            acc[0][0] = __builtin_amdgcn_mfma_f32_16x16x32_bf16(wf[ks], B0, acc[0][0], 0, 0, 0);
            acc[0][1] = __builtin_amdgcn_mfma_f32_16x16x32_bf16(wf[ks], B1, acc[0][1], 0, 0, 0);
          }
          if (ri >= 1) {
            const int ks = ((ri - 1) * 3 + kw) * 2 + cih;
            acc[1][0] = __builtin_amdgcn_mfma_f32_16x16x32_bf16(wf[ks], B0, acc[1][0], 0, 0, 0);
            acc[1][1] = __builtin_amdgcn_mfma_f32_16x16x32_bf16(wf[ks], B1, acc[1][1], 0, 0, 0);
          }
        }
      }
    }

    if constexpr (!FINAL) {
      const int buf = (wi & 1) * 4608;
      f32x4 csadd[2];
      csadd[0] = (f32x4){0,0,0,0}; csadd[1] = (f32x4){0,0,0,0};
#pragma unroll
      for (int o = 0; o < 2; ++o) {
#pragma unroll
        for (int wt = 0; wt < 2; ++wt) {
          u16x4 ev;
#pragma unroll
          for (int r = 0; r < 4; ++r) {
            float z = scR[r] * acc[o][wt][r] + shR[r];
            ev[r] = f2bf(z / (1.f + __expf(-z)));
          }
          *(u16x4*)&epi[buf + ((o * 32) + wt * 16 + col) * 72 + wave * 16 + q * 4] = ev;
#pragma unroll
          for (int r = 0; r < 4; ++r) csadd[wt][r] += bf2f(ev[r]);
        }
      }
      { int cc = wave * 4 + q;
        csv[cc * 32 + col]      += csadd[0];
        csv[cc * 32 + 16 + col] += csadd[1]; }
      if (doS) { STG1_COMMIT(fa0, fa1, aa0, aa1) STG1_COMMIT(fb0, fb1, ab0, ab1) }
      LGKM_BARRIER()
      { int w = t >> 3, s = t & 7;
#pragma unroll
        for (int o = 0; o < 2; ++o) {
          unsigned short* yo = (unsigned short*)outv + (((size_t)b * NH + h + o) * NW + w0) * 64;
          *(u16x8*)&yo[w * 64 + s * 8] = *(const u16x8*)&epi[buf + ((o * 32) + w) * 72 + s * 8];
        }
      }
    } else {
      if (doS) { STGF_COMMIT(va0, va1, aa0, aa1) STGF_COMMIT(vb0, vb1, ab0, ab1) }
      float* outp = (float*)outv;
#pragma unroll
      for (int o = 0; o < 2; ++o) {
        const int rb1 = sl[1 + o];
#pragma unroll
        for (int wt = 0; wt < 2; ++wt) {
          int wcc = wt * 16 + col + 1;
          int gr = (wave * 2 + (q >> 1)) ^ (wcc & 7);
          u16x4 yv = *(const u16x4*)&ring[rb1 + wcc * 64 + gr * 8 + (q & 1) * 4];
#pragma unroll
          for (int r = 0; r < 4; ++r) {
            int co = wave * 16 + q * 4 + r;
            float rv = scoR[r] * acc[o][wt][r] + bf2f(yv[r]);
            float rb_ = scR[r] * rv + shR[r];
            rb_ = fmaxf(rb_, 0.f);
            size_t oi = (((size_t)b * NC + co) * NH + h + o) * NW + w0 + wt * 16 + col;
            outp[oi] = xres[oi] + rb_;
          }
        }
      }
      LGKM_BARRIER()
    }
  }

  if constexpr (!FINAL) {
    const int strip = h0 / 10;
    float* pp = colpart + (((size_t)b * 16 + strip) * NW + w0) * 64;
    int w = t >> 3, g0 = t & 7;
    *(f32x4*)&pp[w * 64 + g0 * 4]       = csv[g0 * 32 + w];
    *(f32x4*)&pp[w * 64 + (g0 + 8) * 4] = csv[(g0 + 8) * 32 + w];
  }
#undef STG1_ISSUE
#undef STG1_COMMIT
#undef STGF_ISSUE
#undef STGF_COMMIT
#undef SLOT
}

// ycol[b][w][c] = sum over 16 strip partials
__global__ void colsum2_kernel(const float* __restrict__ part, float* __restrict__ ycol) {
  int id = blockIdx.x * 256 + threadIdx.x;
  if (id >= NB * NW * NC) return;
  int c = id & 63; int bw = id >> 6; int w = bw % NW; int b = bw / NW;
  const float* p = part + (((size_t)b * 16) * NW + w) * 64 + c;
  float s = 0.f;
#pragma unroll
  for (int st = 0; st < 16; ++st) s += p[(size_t)st * NW * 64];
  ycol[id] = s;
}

// ---------------------------------------------------------------------------
// Fused scores chain: Z (LDS) -> ks -> U -> softmax. One block per b.
// Z[(i*3+kh)*162 + w+1] = ycol[b][w][i] - edge corrections (lw=0,161 zero).
// ---------------------------------------------------------------------------
__global__ __launch_bounds__(256, 1) void scores_all(
    const unsigned short* __restrict__ y, const float* __restrict__ ycol,
    const float* __restrict__ wkst, const float* __restrict__ wqt,
    float* __restrict__ scores)
{
  __shared__ float Z[NC * 3 * 162];   // 124,416 B
  __shared__ float wkl[576];
  __shared__ float ks[NW];
  __shared__ float U[576];
  __shared__ float red[4][64];
  const int b = blockIdx.x, t = threadIdx.x;

  for (int o = t; o < 576; o += 256) wkl[o] = wkst[o];

  // build Z: i-fastest iteration for coalesced ycol/y reads
  for (int idx = t; idx < NC * 3 * 162; idx += 256) {
    int i = idx & 63;
    int rest = idx >> 6;          // rest < 3*162 = 486
    int lw = rest % 162, kh = rest / 162;
    int w = lw - 1;
    float val = 0.f;
    if ((unsigned)w < (unsigned)NW) {
      val = ycol[((size_t)b * NW + w) * 64 + i];
      if (kh == 0) val -= bf2f(y[(((size_t)b * NH + (NH - 1)) * NW + w) * 64 + i]);
      if (kh == 2) val -= bf2f(y[(((size_t)b * NH) * NW + w) * 64 + i]);
    }
    Z[(i * 3 + kh) * 162 + lw] = val;
  }
  __syncthreads();

  // ks[w] = sum_{i,kh,kw} wkl[(kh*3+kw)*64+i] * Z[(i*3+kh)*162 + w+kw]
  if (t < NW) {
    float s = 0.f;
    for (int i = 0; i < NC; ++i) {
#pragma unroll
      for (int kh = 0; kh < 3; ++kh) {
        const float* zr = &Z[(i * 3 + kh) * 162 + t];
        s += wkl[(kh * 3 + 0) * 64 + i] * zr[0]
           + wkl[(kh * 3 + 1) * 64 + i] * zr[1]
           + wkl[(kh * 3 + 2) * 64 + i] * zr[2];
      }
    }
    ks[t] = s;
  }
  __syncthreads();

  // U[jj*64+i] = sum_w Z[(i*3+kh)*162 + w+kw] * ks[w],  jj = kh*3+kw
  for (int o = t; o < 576; o += 256) {
    int i = o & 63, jj = o >> 6;
    int kh = jj / 3, kw = jj % 3;
    const float* zr = &Z[(i * 3 + kh) * 162 + kw];
    float s = 0.f;
    for (int w = 0; w < NW; ++w) s += zr[w] * ks[w];
    U[o] = s;
  }
  __syncthreads();

  // f[c] = scale * sum_tau wqt[tau*64+c] * U[tau]; softmax over c
  {
    int c = t & 63, p = t >> 6;
    float s = 0.f;
    for (int tau = p * 144; tau < p * 144 + 144; ++tau)
      s += wqt[(size_t)tau * 64 + c] * U[tau];
    red[p][c] = s;
  }
  __syncthreads();
  if (t < NC) {
    const float scale = 1.0f / (sqrtf((float)NW) * (float)NH * (float)NH);
    float f = (red[0][t] + red[1][t] + red[2][t] + red[3][t]) * scale;
    float mx = f;
#pragma unroll
    for (int off = 32; off; off >>= 1) mx = fmaxf(mx, __shfl_xor(mx, off));
    float e = __expf(f - mx);
    float sm = e;
#pragma unroll
    for (int off = 32; off; off >>= 1) sm += __shfl_xor(sm, off);
    scores[b * NC + t] = e / sm;
  }
}

extern "C" void kernel_launch(void* const* d_in, const int* in_sizes, int n_in,
                              void* d_out, int out_size, void* d_ws, size_t ws_size,
                              hipStream_t stream) {
  const float* x  = (const float*)d_in[0];
  const float* w1 = (const float*)d_in[1];
  const float* g1 = (const float*)d_in[2];
  const float* b1 = (const float*)d_in[3];
  const float* m1 = (const float*)d_in[4];
  const float* v1 = (const float*)d_in[5];
  const float* wq = (const float*)d_in[6];
  const float* wk = (const float*)d_in[7];
  const float* wv = (const float*)d_in[8];
  const float* g2 = (const float*)d_in[9];
  const float* b2 = (const float*)d_in[10];
  const float* m2 = (const float*)d_in[11];
  const float* v2 = (const float*)d_in[12];
  float* out = (float*)d_out;

  // ws: apk1 | apk2 | wqt | wkst | ycol | scr | part | y
  unsigned short* apk1 = (unsigned short*)d_ws;
  unsigned short* apk2 = apk1 + 36864;
  float* wqt  = (float*)(apk2 + 36864);
  float* wkst = wqt + 36864;
  float* ycol = wkst + 576;
  float* scr  = ycol + NB * NW * NC;
  float* part = scr + 1024;                       // NB*16*NW*64 f32 = 10.5 MB
  unsigned short* y = (unsigned short*)(part + (size_t)NB * 16 * NW * 64);

  pack_w_kernel3<<<dim3(435), 256, 0, stream>>>(w1, wv, wq, wk, apk1, apk2, wqt, wkst);

  conv3x3_mfma7<false><<<dim3(1280), 256, 0, stream>>>(
      nullptr, x, apk1, g1, b1, m1, v1, (void*)y, nullptr, nullptr, part);

  colsum2_kernel<<<dim3((NB * NW * NC + 255) / 256), 256, 0, stream>>>(part, ycol);
  scores_all<<<dim3(NB), 256, 0, stream>>>(y, ycol, wkst, wqt, scr);

  conv3x3_mfma7<true><<<dim3(1280), 256, 0, stream>>>(
      y, nullptr, apk2, g2, b2, m2, v2, (void*)out, scr, x, nullptr);
}

// Round 13
// 150.151 us; speedup vs baseline: 1.1404x; 1.1404x over previous
//
#include <hip/hip_runtime.h>
#include <hip/hip_bf16.h>
#include <math.h>

#define NB 16
#define NC 64
#define NH 160
#define NW 160

typedef __attribute__((ext_vector_type(8))) short bf16x8;
typedef __attribute__((ext_vector_type(4))) float f32x4;
typedef __attribute__((ext_vector_type(8))) unsigned short u16x8;
typedef __attribute__((ext_vector_type(4))) unsigned short u16x4;

__device__ __forceinline__ unsigned short f2bf(float v) {
  union { __hip_bfloat16 b; unsigned short u; } cv; cv.b = __float2bfloat16(v); return cv.u;
}
__device__ __forceinline__ float bf2f(unsigned short u) {
  union { unsigned u; float f; } cv; cv.u = ((unsigned)u) << 16; return cv.f;
}

// lgkm-only barrier: no vmcnt drain of global stores (T3/T4); rule-18 fencing
#define LGKM_BARRIER()                                  \
  asm volatile("s_waitcnt lgkmcnt(0)" ::: "memory");    \
  __builtin_amdgcn_sched_barrier(0);                    \
  __builtin_amdgcn_s_barrier();                         \
  __builtin_amdgcn_sched_barrier(0);

// ---------------------------------------------------------------------------
// Pack kernel: apkA/apkB (A-fragment weights), wqt (wq transposed), wkst.
// ---------------------------------------------------------------------------
__global__ void pack_w_kernel3(const float* __restrict__ wA, const float* __restrict__ wB,
                               const float* __restrict__ wq, const float* __restrict__ wk,
                               unsigned short* __restrict__ apkA, unsigned short* __restrict__ apkB,
                               float* __restrict__ wqt, float* __restrict__ wkst) {
  int idx = blockIdx.x * 256 + threadIdx.x;
  if (idx < 2 * 36864) {
    const float* w = (idx < 36864) ? wA : wB;
    unsigned short* apk = (idx < 36864) ? apkA : apkB;
    int i = (idx < 36864) ? idx : idx - 36864;
    int j = i & 7, l = (i >> 3) & 63, rest = i >> 9;
    int ks = rest % 18, ct = rest / 18;
    int cih = ks & 1, tap = ks >> 1, kh = tap / 3, kw = tap % 3;
    int co = ct * 16 + (l & 15), ci = cih * 32 + (l >> 4) * 8 + j;
    apk[i] = f2bf(w[(((size_t)co * NC + ci) * 3 + kh) * 3 + kw]);
  } else if (idx < 3 * 36864) {
    int i2 = idx - 2 * 36864;
    int c = i2 & 63, tau = i2 >> 6;
    int i = tau & 63, jj = tau >> 6;
    wqt[i2] = wq[(size_t)c * 576 + i * 9 + jj];
  } else if (idx < 3 * 36864 + 576) {
    int i3 = idx - 3 * 36864;
    int i = i3 & 63, jj = i3 >> 6;
    float s = 0.f;
    for (int cj = 0; cj < NC; ++cj) s += wk[(size_t)cj * 576 + i * 9 + jj];
    wkst[i3] = s;
  }
}

// ---------------------------------------------------------------------------
// Sliding-row implicit-GEMM conv3x3 (SAME) via MFMA 16x16x32 bf16.
// R9 structure VERBATIM (best measured): issue-at-window-start,
// commit-at-window-end, lgkm-only barriers, epi dbuf, fused NCHW staging
// in conv1, all 18 weight frags resident.
// ---------------------------------------------------------------------------
template<bool FINAL>
__global__ __launch_bounds__(256, 2) void conv3x3_mfma7(
    const unsigned short* __restrict__ in_nhwc, const float* __restrict__ in_nchw,
    const unsigned short* __restrict__ apk,
    const float* __restrict__ gg, const float* __restrict__ bbeta,
    const float* __restrict__ mmean, const float* __restrict__ vvar,
    void* __restrict__ outv, const float* __restrict__ scores,
    const float* __restrict__ xres, float* __restrict__ colpart)
{
  __shared__ unsigned short ring[6 * 34 * 64];                 // 26,112 B
  __shared__ unsigned short epi[FINAL ? 8 : 2 * 64 * 72];      // 18,432 B (conv1, dbuf)
  __shared__ f32x4 csv[FINAL ? 1 : 512];                       // 8,192 B (conv1)

  const int t = threadIdx.x, lane = t & 63, wave = t >> 6;
  const int q = lane >> 4, col = lane & 15;

  int g = blockIdx.x;                    // 1280 = 8 * 160, bijective XCD swizzle
  int sw = (g & 7) * 160 + (g >> 3);
  const int b = sw / 80;
  int rem = sw % 80;
  const int h0 = (rem / 5) * 10, w0 = (rem % 5) * 32;

  float scR[4], shR[4], scoR[4];
#pragma unroll
  for (int r = 0; r < 4; ++r) {
    int co = wave * 16 + q * 4 + r;
    float s = gg[co] * rsqrtf(vvar[co] + 1e-5f);
    scR[r] = s; shR[r] = bbeta[co] - mmean[co] * s;
    scoR[r] = FINAL ? scores[b * NC + co] : 0.f;
  }

  bf16x8 wf[18];
#pragma unroll
  for (int ks = 0; ks < 18; ++ks)
    wf[ks] = *(const bf16x8*)&apk[((size_t)(wave * 18 + ks) * 64 + lane) * 8];

  const unsigned short* inb = FINAL ? in_nhwc + (size_t)b * NH * NW * 64 : nullptr;
  const float* xb = FINAL ? nullptr : in_nchw + (size_t)b * NC * NH * NW;

#define SLOT(R) ((int)((unsigned)((R) + 1) % 6u) * 2176)

  // ---- FINAL staging: NHWC bf16, u16x8 vector loads ----
#define STGF_ISSUE(ROW, V0, V1, A0, A1)                                       \
  { int row_ = (ROW);                                                         \
    bool rowok_ = (unsigned)row_ < (unsigned)NH;                              \
    int slot_ = SLOT(row_);                                                   \
    { int wcc = t >> 3, s8 = t & 7; int wsrc = w0 + wcc - 1;                  \
      A0 = slot_ + wcc * 64 + ((s8 ^ (wcc & 7)) << 3);                        \
      V0 = (u16x8){};                                                         \
      if (rowok_ && (unsigned)wsrc < (unsigned)NW)                            \
        V0 = *(const u16x8*)&inb[((size_t)row_ * NW + wsrc) * 64 + s8 * 8];   \
    }                                                                         \
    if (t < 16) { int c = 256 + t; int wcc = c >> 3, s8 = c & 7;              \
      int wsrc = w0 + wcc - 1;                                                \
      A1 = slot_ + wcc * 64 + ((s8 ^ (wcc & 7)) << 3);                        \
      V1 = (u16x8){};                                                         \
      if (rowok_ && (unsigned)wsrc < (unsigned)NW)                            \
        V1 = *(const u16x8*)&inb[((size_t)row_ * NW + wsrc) * 64 + s8 * 8];   \
    } }
#define STGF_COMMIT(V0, V1, A0, A1)                                           \
  *(u16x8*)&ring[A0] = V0;                                                    \
  if (t < 16) *(u16x8*)&ring[A1] = V1;

  // ---- conv1 staging: NCHW f32 x, 8 dword loads (34-lane coalesced runs) ----
#define STG1_ISSUE(ROW, F0, F1, A0, A1)                                       \
  { int row_ = (ROW);                                                         \
    bool rowok_ = (unsigned)row_ < (unsigned)NH;                              \
    int slot_ = SLOT(row_);                                                   \
    { int wcc = t % 34, s8 = t / 34; int wsrc = w0 + wcc - 1;                 \
      A0 = slot_ + wcc * 64 + ((s8 ^ (wcc & 7)) << 3);                        \
      bool ok_ = rowok_ && (unsigned)wsrc < (unsigned)NW;                     \
      if (ok_) {                                                              \
        const float* xp_ = xb + ((size_t)(s8 * 8) * NH + row_) * NW + wsrc;   \
        _Pragma("unroll") for (int j_ = 0; j_ < 8; ++j_)                      \
          F0[j_] = xp_[(size_t)j_ * NH * NW];                                 \
      } else {                                                                \
        _Pragma("unroll") for (int j_ = 0; j_ < 8; ++j_) F0[j_] = 0.f;        \
      }                                                                       \
    }                                                                         \
    if (t < 16) { int wcc = 18 + t; int wsrc = w0 + wcc - 1;                  \
      A1 = slot_ + wcc * 64 + ((7 ^ (wcc & 7)) << 3);                         \
      bool ok_ = rowok_ && (unsigned)wsrc < (unsigned)NW;                     \
      if (ok_) {                                                              \
        const float* xp_ = xb + ((size_t)56 * NH + row_) * NW + wsrc;         \
        _Pragma("unroll") for (int j_ = 0; j_ < 8; ++j_)                      \
          F1[j_] = xp_[(size_t)j_ * NH * NW];                                 \
      } else {                                                                \
        _Pragma("unroll") for (int j_ = 0; j_ < 8; ++j_) F1[j_] = 0.f;        \
      }                                                                       \
    } }
#define STG1_COMMIT(F0, F1, A0, A1)                                           \
  { u16x8 pv_;                                                                \
    _Pragma("unroll") for (int j_ = 0; j_ < 8; ++j_) pv_[j_] = f2bf(F0[j_]);  \
    *(u16x8*)&ring[A0] = pv_; }                                               \
  if (t < 16) { u16x8 pv_;                                                    \
    _Pragma("unroll") for (int j_ = 0; j_ < 8; ++j_) pv_[j_] = f2bf(F1[j_]);  \
    *(u16x8*)&ring[A1] = pv_; }

  if constexpr (!FINAL) {
    csv[t] = (f32x4){0.f, 0.f, 0.f, 0.f};
    csv[t + 256] = (f32x4){0.f, 0.f, 0.f, 0.f};
  }

  // prologue: stage rows h0-1 .. h0+2
  if constexpr (FINAL) {
    for (int rr = -1; rr <= 2; ++rr) {
      u16x8 v0, v1 = {}; int a0, a1 = 0;
      STGF_ISSUE(h0 + rr, v0, v1, a0, a1)
      STGF_COMMIT(v0, v1, a0, a1)
    }
  } else {
    for (int rr = -1; rr <= 2; ++rr) {
      float f0[8], f1[8]; int a0, a1 = 0;
      STG1_ISSUE(h0 + rr, f0, f1, a0, a1)
      STG1_COMMIT(f0, f1, a0, a1)
    }
  }
  LGKM_BARRIER()

  for (int wi = 0; wi < 5; ++wi) {
    const int h = h0 + wi * 2;
    const bool doS = (wi < 4);

    u16x8 va0, va1 = {}, vb0, vb1 = {}; int aa0, aa1 = 0, ab0, ab1 = 0;
    float fa0[8], fa1[8], fb0[8], fb1[8];
    if (doS) {
      if constexpr (FINAL) {
        STGF_ISSUE(h + 3, va0, va1, aa0, aa1)
        STGF_ISSUE(h + 4, vb0, vb1, ab0, ab1)
      } else {
        STG1_ISSUE(h + 3, fa0, fa1, aa0, aa1)
        STG1_ISSUE(h + 4, fb0, fb1, ab0, ab1)
      }
    }

    const int sl[4] = { SLOT(h - 1), SLOT(h), SLOT(h + 1), SLOT(h + 2) };
    f32x4 acc[2][2];
#pragma unroll
    for (int o = 0; o < 2; ++o) { acc[o][0] = (f32x4){0,0,0,0}; acc[o][1] = (f32x4){0,0,0,0}; }

#pragma unroll
    for (int ri = 0; ri < 4; ++ri) {
#pragma unroll
      for (int kw = 0; kw < 3; ++kw) {
#pragma unroll
        for (int cih = 0; cih < 2; ++cih) {
          const int wcb = col + kw;
          const int ea = sl[ri] + wcb * 64 + (((cih << 2) + q) ^ (wcb & 7)) * 8;
          const bf16x8* bp = (const bf16x8*)&ring[ea];
          bf16x8 B0 = bp[0], B1 = bp[128];
          if (ri <= 2) {
            const int ks = (ri * 3 + kw) * 2 + cih;
            acc[0][0] = __builtin_amdgcn_mfma_f32_16x16x32_bf16(wf[ks], B0, acc[0][0], 0, 0, 0);
            acc[0][1] = __builtin_amdgcn_mfma_f32_16x16x32_bf16(wf[ks], B1, acc[0][1], 0, 0, 0);
          }
          if (ri >= 1) {
            const int ks = ((ri - 1) * 3 + kw) * 2 + cih;
            acc[1][0] = __builtin_amdgcn_mfma_f32_16x16x32_bf16(wf[ks], B0, acc[1][0], 0, 0, 0);
            acc[1][1] = __builtin_amdgcn_mfma_f32_16x16x32_bf16(wf[ks], B1, acc[1][1], 0, 0, 0);
          }
        }
      }
    }

    if constexpr (!FINAL) {
      const int buf = (wi & 1) * 4608;
      f32x4 csadd[2];
      csadd[0] = (f32x4){0,0,0,0}; csadd[1] = (f32x4){0,0,0,0};
#pragma unroll
      for (int o = 0; o < 2; ++o) {
#pragma unroll
        for (int wt = 0; wt < 2; ++wt) {
          u16x4 ev;
#pragma unroll
          for (int r = 0; r < 4; ++r) {
            float z = scR[r] * acc[o][wt][r] + shR[r];
            ev[r] = f2bf(z / (1.f + __expf(-z)));
          }
          *(u16x4*)&epi[buf + ((o * 32) + wt * 16 + col) * 72 + wave * 16 + q * 4] = ev;
#pragma unroll
          for (int r = 0; r < 4; ++r) csadd[wt][r] += bf2f(ev[r]);
        }
      }
      { int cc = wave * 4 + q;
        csv[cc * 32 + col]      += csadd[0];
        csv[cc * 32 + 16 + col] += csadd[1]; }
      if (doS) { STG1_COMMIT(fa0, fa1, aa0, aa1) STG1_COMMIT(fb0, fb1, ab0, ab1) }
      LGKM_BARRIER()
      { int w = t >> 3, s = t & 7;
#pragma unroll
        for (int o = 0; o < 2; ++o) {
          unsigned short* yo = (unsigned short*)outv + (((size_t)b * NH + h + o) * NW + w0) * 64;
          *(u16x8*)&yo[w * 64 + s * 8] = *(const u16x8*)&epi[buf + ((o * 32) + w) * 72 + s * 8];
        }
      }
    } else {
      if (doS) { STGF_COMMIT(va0, va1, aa0, aa1) STGF_COMMIT(vb0, vb1, ab0, ab1) }
      float* outp = (float*)outv;
#pragma unroll
      for (int o = 0; o < 2; ++o) {
        const int rb1 = sl[1 + o];
#pragma unroll
        for (int wt = 0; wt < 2; ++wt) {
          int wcc = wt * 16 + col + 1;
          int gr = (wave * 2 + (q >> 1)) ^ (wcc & 7);
          u16x4 yv = *(const u16x4*)&ring[rb1 + wcc * 64 + gr * 8 + (q & 1) * 4];
#pragma unroll
          for (int r = 0; r < 4; ++r) {
            int co = wave * 16 + q * 4 + r;
            float rv = scoR[r] * acc[o][wt][r] + bf2f(yv[r]);
            float rb_ = scR[r] * rv + shR[r];
            rb_ = fmaxf(rb_, 0.f);
            size_t oi = (((size_t)b * NC + co) * NH + h + o) * NW + w0 + wt * 16 + col;
            outp[oi] = xres[oi] + rb_;
          }
        }
      }
      LGKM_BARRIER()
    }
  }

  if constexpr (!FINAL) {
    const int strip = h0 / 10;
    float* pp = colpart + (((size_t)b * 16 + strip) * NW + w0) * 64;
    int w = t >> 3, g0 = t & 7;
    *(f32x4*)&pp[w * 64 + g0 * 4]       = csv[g0 * 32 + w];
    *(f32x4*)&pp[w * 64 + (g0 + 8) * 4] = csv[(g0 + 8) * 32 + w];
  }
#undef STG1_ISSUE
#undef STG1_COMMIT
#undef STGF_ISSUE
#undef STGF_COMMIT
#undef SLOT
}

// ycol[b][w][c] = sum over 16 strip partials
__global__ void colsum2_kernel(const float* __restrict__ part, float* __restrict__ ycol) {
  int id = blockIdx.x * 256 + threadIdx.x;
  if (id >= NB * NW * NC) return;
  int c = id & 63; int bw = id >> 6; int w = bw % NW; int b = bw / NW;
  const float* p = part + (((size_t)b * 16) * NW + w) * 64 + c;
  float s = 0.f;
#pragma unroll
  for (int st = 0; st < 16; ++st) s += p[(size_t)st * NW * 64];
  ycol[id] = s;
}

// Z helper
__device__ __forceinline__ float zval(const float* __restrict__ ycol,
                                      const unsigned short* __restrict__ y,
                                      int b, int i, int kh, int wp) {
  float z = ycol[((size_t)b * NW + wp) * 64 + i];
  if (kh == 0) z -= bf2f(y[(((size_t)b * NH + (NH - 1)) * NW + wp) * 64 + i]);
  if (kh == 2) z -= bf2f(y[(((size_t)b * NH) * NW + wp) * 64 + i]);
  return z;
}

// S2: ks[b,w]
__global__ __launch_bounds__(256) void ks_kernel(
    const float* __restrict__ ycol, const unsigned short* __restrict__ y,
    const float* __restrict__ wkst, float* __restrict__ ks)
{
  int id = blockIdx.x * 4 + (threadIdx.x >> 6);
  int lane = threadIdx.x & 63;
  int b = id / NW, w = id % NW;
  float s = 0.f;
#pragma unroll
  for (int jj = 0; jj < 9; ++jj) {
    int kh = jj / 3, kw = jj % 3;
    int wp = w + kw - 1;
    if ((unsigned)wp < (unsigned)NW)
      s += wkst[jj * 64 + lane] * zval(ycol, y, b, lane, kh, wp);
  }
#pragma unroll
  for (int off = 32; off; off >>= 1) s += __shfl_xor(s, off);
  if (lane == 0) ks[id] = s;
}

// S3: U[b][jj][i]
__global__ __launch_bounds__(256) void u_kernel(
    const float* __restrict__ ycol, const unsigned short* __restrict__ y,
    const float* __restrict__ ks, float* __restrict__ U)
{
  __shared__ float red[4][64];
  int bid = blockIdx.x;
  int b = bid / 9, jj = bid % 9;
  int kh = jj / 3, kw = jj % 3;
  int i = threadIdx.x & 63, ch = threadIdx.x >> 6;
  float s = 0.f;
  for (int w = ch * 40; w < ch * 40 + 40; ++w) {
    int wp = w + kw - 1;
    if ((unsigned)wp < (unsigned)NW)
      s += zval(ycol, y, b, i, kh, wp) * ks[b * NW + w];
  }
  red[ch][i] = s;
  __syncthreads();
  if (threadIdx.x < 64)
    U[((size_t)b * 9 + jj) * 64 + threadIdx.x] =
        red[0][threadIdx.x] + red[1][threadIdx.x] + red[2][threadIdx.x] + red[3][threadIdx.x];
}

// S4: scores
__global__ __launch_bounds__(256) void scores_kernel2(
    const float* __restrict__ wqt, const float* __restrict__ U,
    float* __restrict__ scores)
{
  __shared__ float red[4][64];
  int b = blockIdx.x;
  int c = threadIdx.x & 63, p = threadIdx.x >> 6;
  const float* Ub = U + (size_t)b * 576;
  float s = 0.f;
  for (int tau = p * 144; tau < p * 144 + 144; ++tau)
    s += wqt[(size_t)tau * 64 + c] * Ub[tau];
  red[p][c] = s;
  __syncthreads();
  if (threadIdx.x < 64) {
    const float scale = 1.0f / (sqrtf((float)NW) * (float)NH * (float)NH);
    float f = (red[0][c] + red[1][c] + red[2][c] + red[3][c]) * scale;
    float mx = f;
#pragma unroll
    for (int off = 32; off; off >>= 1) mx = fmaxf(mx, __shfl_xor(mx, off));
    float e = __expf(f - mx);
    float sm = e;
#pragma unroll
    for (int off = 32; off; off >>= 1) sm += __shfl_xor(sm, off);
    scores[b * NC + c] = e / sm;
  }
}

extern "C" void kernel_launch(void* const* d_in, const int* in_sizes, int n_in,
                              void* d_out, int out_size, void* d_ws, size_t ws_size,
                              hipStream_t stream) {
  const float* x  = (const float*)d_in[0];
  const float* w1 = (const float*)d_in[1];
  const float* g1 = (const float*)d_in[2];
  const float* b1 = (const float*)d_in[3];
  const float* m1 = (const float*)d_in[4];
  const float* v1 = (const float*)d_in[5];
  const float* wq = (const float*)d_in[6];
  const float* wk = (const float*)d_in[7];
  const float* wv = (const float*)d_in[8];
  const float* g2 = (const float*)d_in[9];
  const float* b2 = (const float*)d_in[10];
  const float* m2 = (const float*)d_in[11];
  const float* v2 = (const float*)d_in[12];
  float* out = (float*)d_out;

  // ws: apk1 | apk2 | wqt | wkst | ycol | ks | U | scr | part | y
  unsigned short* apk1 = (unsigned short*)d_ws;
  unsigned short* apk2 = apk1 + 36864;
  float* wqt  = (float*)(apk2 + 36864);
  float* wkst = wqt + 36864;
  float* ycol = wkst + 576;
  float* ks   = ycol + NB * NW * NC;
  float* U    = ks + NB * NW;
  float* scr  = U + NB * 576;
  float* part = scr + 1024;                       // NB*16*NW*64 f32 = 10.5 MB
  unsigned short* y = (unsigned short*)(part + (size_t)NB * 16 * NW * 64);

  pack_w_kernel3<<<dim3(435), 256, 0, stream>>>(w1, wv, wq, wk, apk1, apk2, wqt, wkst);

  conv3x3_mfma7<false><<<dim3(1280), 256, 0, stream>>>(
      nullptr, x, apk1, g1, b1, m1, v1, (void*)y, nullptr, nullptr, part);

  colsum2_kernel<<<dim3((NB * NW * NC + 255) / 256), 256, 0, stream>>>(part, ycol);
  ks_kernel<<<dim3(NB * NW / 4), 256, 0, stream>>>(ycol, y, wkst, ks);
  u_kernel<<<dim3(NB * 9), 256, 0, stream>>>(ycol, y, ks, U);
  scores_kernel2<<<dim3(NB), 256, 0, stream>>>(wqt, U, scr);

  conv3x3_mfma7<true><<<dim3(1280), 256, 0, stream>>>(
      y, nullptr, apk2, g2, b2, m2, v2, (void*)out, scr, x, nullptr);
}